// Round 9
// baseline (31800.037 us; speedup 1.0000x reference)
//
#include <hip/hip_runtime.h>

typedef unsigned short u16;

__device__ __forceinline__ float bf2f(u16 h) {
    union { unsigned int u; float f; } v; v.u = ((unsigned int)h) << 16; return v.f;
}
__device__ __forceinline__ u16 f2bf(float f) {
    union { float f; unsigned int u; } v; v.f = f;
    unsigned int r = v.u + 0x7fffu + ((v.u >> 16) & 1u);
    return (u16)(r >> 16);
}
__device__ __forceinline__ float ldin(const void* p, size_t i, int fl) {
    return fl ? bf2f(((const u16*)p)[i]) : ((const float*)p)[i];
}

__device__ __forceinline__ float waveSum(float v) {
#pragma unroll
    for (int o = 32; o > 0; o >>= 1) v += __shfl_down(v, o);
    return v;
}
__device__ __forceinline__ float waveMax(float v) {
#pragma unroll
    for (int o = 32; o > 0; o >>= 1) v = fmaxf(v, __shfl_down(v, o));
    return v;
}
__device__ __forceinline__ int waveSumI(int v) {
#pragma unroll
    for (int o = 32; o > 0; o >>= 1) v += __shfl_down(v, o);
    return v;
}

// ---------------- dtype detection: flag=1 if inputs bf16, 0 if f32 ----------------
__global__ __launch_bounds__(256) void detect_k(const u16* __restrict__ x, int* __restrict__ flag) {
    __shared__ int cnt[4];
    int c = 0;
    for (int i = threadIdx.x; i < 8192; i += 256) {
        u16 e = x[i * 2];
        int ex = (e >> 7) & 0xFF;
        c += (ex == 0 || (ex >= 100 && ex <= 150)) ? 1 : 0;
    }
    c = waveSumI(c);
    if ((threadIdx.x & 63) == 0) cnt[threadIdx.x >> 6] = c;
    __syncthreads();
    if (threadIdx.x == 0)
        flag[0] = ((cnt[0] + cnt[1] + cnt[2] + cnt[3]) > 4915) ? 1 : 0;
}

// ---------------- GroupNorm stats — frame map t*4+b (verified from reference) ----------------
__global__ __launch_bounds__(256) void gn_stats(const void* __restrict__ x, float* __restrict__ stat,
                                                const int* __restrict__ flag) {
    __shared__ float red[8];
    const int gg = blockIdx.y, chunk = blockIdx.x;
    const int b = gg >> 2, g = gg & 3;
    const int fl = flag[0];
    float s = 0.f, s2 = 0.f;
    for (int pp = 0; pp < 48; pp++) {
        int p = chunk * 48 + pp;
        int t = p >> 7, cc = p & 127;
        size_t rowbase = (size_t)((t * 4 + b) * 512 + g * 128 + cc) * 2304;
        for (int vi = threadIdx.x; vi < 288; vi += 256) {
            size_t base = rowbase + (size_t)vi * 8;
            float f[8];
            if (fl) {
                union { int4 v4; u16 u[8]; } tv;
                tv.v4 = *(const int4*)((const u16*)x + base);
#pragma unroll
                for (int j = 0; j < 8; j++) f[j] = bf2f(tv.u[j]);
            } else {
                const float* fp = (const float*)x + base;
                float4 a = *(const float4*)fp;
                float4 c4 = *(const float4*)(fp + 4);
                f[0]=a.x; f[1]=a.y; f[2]=a.z; f[3]=a.w; f[4]=c4.x; f[5]=c4.y; f[6]=c4.z; f[7]=c4.w;
            }
#pragma unroll
            for (int j = 0; j < 8; j++) { s += f[j]; s2 += f[j] * f[j]; }
        }
    }
    s = waveSum(s); s2 = waveSum(s2);
    int wid = threadIdx.x >> 6;
    if ((threadIdx.x & 63) == 0) { red[wid] = s; red[wid + 4] = s2; }
    __syncthreads();
    if (threadIdx.x == 0) {
        atomicAdd(&stat[gg], red[0] + red[1] + red[2] + red[3]);
        atomicAdd(&stat[16 + gg], red[4] + red[5] + red[6] + red[7]);
    }
}

// ---------------- per-(b,c) affine ----------------
__global__ void gn_ab(const float* __restrict__ stat, const void* __restrict__ scale,
                      const void* __restrict__ bias, float2* __restrict__ ab,
                      const int* __restrict__ flag) {
    int idx = blockIdx.x * 256 + threadIdx.x;
    int b = idx >> 9, c = idx & 511, g = c >> 7, gg = b * 4 + g;
    const int fl = flag[0];
    const float invN = 1.f / 884736.f;
    float mean = stat[gg] * invN;
    float var  = stat[16 + gg] * invN - mean * mean;
    float rstd = rsqrtf(var + 1e-6f);
    float a = rstd * ldin(scale, c, fl);
    ab[idx] = make_float2(a, ldin(bias, c, fl) - mean * a);
}

// ---------------- naive conv1x1; F32OUT selects output store type ----------------
template<int F32OUT>
__global__ __launch_bounds__(256) void qkv_naive(const void* __restrict__ w, const void* __restrict__ bias,
                                                 const void* __restrict__ x, const float2* __restrict__ ab,
                                                 void* __restrict__ outb, int Mtot, int m_off,
                                                 int b, const int* __restrict__ flag) {
    int m = blockIdx.x * 256 + threadIdx.x;
    if (m >= Mtot) return;
    int o = blockIdx.y;
    int mm = m + m_off;
    int t = mm / 2304, pos = mm - t * 2304;
    const int fl = flag[0];
    size_t xrow = (size_t)((t * 4 + b) * 512) * 2304 + pos;
    const float2* abp = ab + b * 512;
    float acc = 0.f;
    for (int c = 0; c < 512; c++) {
        float2 A = abp[c];
        float xv = ldin(x, xrow + (size_t)c * 2304, fl);
        float wv = ldin(w, (size_t)o * 512 + c, fl);
        acc += wv * (A.x * xv + A.y);
    }
    acc += ldin(bias, o, fl);
    if (F32OUT) ((float*)outb)[(size_t)o * Mtot + m] = acc;
    else        ((u16*)outb)[(size_t)o * Mtot + m] = f2bf(acc);
}

// ---------------- naive scores: S[n][m] = rs * sum_c q[c][n]*k[c][m] (q is f32) ----------------
__global__ __launch_bounds__(256) void s_naive(const float* __restrict__ qb, const u16* __restrict__ kb,
                                               u16* __restrict__ sb) {
    int m = blockIdx.x * 256 + threadIdx.x;
    int n = blockIdx.y;
    float acc = 0.f;
    for (int c = 0; c < 512; c++)
        acc += qb[(size_t)c * 2304 + n] * bf2f(kb[(size_t)c * 6912 + m]);
    sb[(size_t)n * 6912 + m] = f2bf(acc * 0.044194173824159216f);
}

// ---------------- row softmax over m=6912, bf16 in-place ----------------
__global__ __launch_bounds__(256) void softmax_k(u16* __restrict__ sb) {
    __shared__ float row[6912];
    __shared__ float red[8];
    u16* p = sb + (size_t)blockIdx.x * 6912;
    const int tid = threadIdx.x;
    float mx = -3.0e38f;
    for (int vi = tid; vi < 864; vi += 256) {
        union { int4 v4; u16 u[8]; } tv;
        tv.v4 = *(const int4*)(p + vi * 8);
#pragma unroll
        for (int j = 0; j < 8; j++) { float f = bf2f(tv.u[j]); row[vi * 8 + j] = f; mx = fmaxf(mx, f); }
    }
    mx = waveMax(mx);
    if ((tid & 63) == 0) red[tid >> 6] = mx;
    __syncthreads();
    mx = fmaxf(fmaxf(red[0], red[1]), fmaxf(red[2], red[3]));
    __syncthreads();
    float sum = 0.f;
    for (int i = tid; i < 6912; i += 256) {
        float e = __expf(row[i] - mx);
        row[i] = e; sum += e;
    }
    sum = waveSum(sum);
    if ((tid & 63) == 0) red[4 + (tid >> 6)] = sum;
    __syncthreads();
    float inv = 1.f / (red[4] + red[5] + red[6] + red[7]);
    for (int vi = tid; vi < 864; vi += 256) {
        union { int4 v4; u16 u[8]; } tv;
#pragma unroll
        for (int j = 0; j < 8; j++) tv.u[j] = f2bf(row[vi * 8 + j] * inv);
        *(int4*)(p + vi * 8) = tv.v4;
    }
}

// ---------------- naive O: O[c][n] = sum_m v[c][m]*attn[n][m] ----------------
__global__ __launch_bounds__(256) void o_naive(const u16* __restrict__ vb, const u16* __restrict__ sb,
                                               u16* __restrict__ ob) {
    int wv = threadIdx.x >> 6, lane = threadIdx.x & 63;
    int n = blockIdx.x * 4 + wv;
    int c = blockIdx.y;
    const u16* vr = vb + (size_t)c * 6912;
    const u16* ar = sb + (size_t)n * 6912;
    float acc = 0.f;
    for (int m = lane; m < 6912; m += 64)
        acc += bf2f(vr[m]) * bf2f(ar[m]);
    acc = waveSum(acc);
    if (lane == 0) ob[(size_t)c * 2304 + n] = f2bf(acc);
}

// ---------------- proj + skip, FLOAT32 output ----------------
__global__ __launch_bounds__(256) void proj_naive(const void* __restrict__ pw, const void* __restrict__ pbias,
                                                  const u16* __restrict__ ob, const float* __restrict__ qb,
                                                  float* __restrict__ out, int b, const int* __restrict__ flag) {
    int n = blockIdx.x * 256 + threadIdx.x;
    int o = blockIdx.y;
    const int fl = flag[0];
    float acc = 0.f;
    for (int c = 0; c < 512; c++)
        acc += ldin(pw, (size_t)o * 512 + c, fl) * bf2f(ob[(size_t)c * 2304 + n]);
    acc += ldin(pbias, o, fl) + qb[(size_t)o * 2304 + n];
    out[(size_t)b * 512 * 2304 + (size_t)o * 2304 + n] = acc;
}

extern "C" void kernel_launch(void* const* d_in, const int* in_sizes, int n_in,
                              void* d_out, int out_size, void* d_ws, size_t ws_size,
                              hipStream_t stream) {
    const void* x   = d_in[0];
    const void* nsc = d_in[1];
    const void* nbi = d_in[2];
    const void* qw  = d_in[3];
    const void* qb_ = d_in[4];
    const void* kw  = d_in[5];
    const void* kb_ = d_in[6];
    const void* vw  = d_in[7];
    const void* vb_ = d_in[8];
    const void* pw  = d_in[9];
    const void* pb_ = d_in[10];
    float* out = (float*)d_out;   // reference output dtype is FLOAT32

    // workspace (~51 MiB)
    char* w = (char*)d_ws;
    int*    flag = (int*)w;     w += 256;
    float*  stat = (float*)w;   w += 256;
    float2* ab   = (float2*)w;  w += 2048 * sizeof(float2);
    float* qbuf = (float*)w;  w += (size_t)512 * 2304 * 4;   // f32 skip, 4.5 MiB
    u16* kbuf = (u16*)w;  w += (size_t)512 * 6912 * 2;
    u16* vbuf = (u16*)w;  w += (size_t)512 * 6912 * 2;
    u16* obuf = (u16*)w;  w += (size_t)512 * 2304 * 2;
    u16* sbuf = (u16*)w;

    detect_k<<<1, 256, 0, stream>>>((const u16*)x, flag);
    hipMemsetAsync(stat, 0, 32 * sizeof(float), stream);
    gn_stats<<<dim3(8, 16), 256, 0, stream>>>(x, stat, flag);
    gn_ab<<<8, 256, 0, stream>>>(stat, nsc, nbi, ab, flag);

    for (int b = 0; b < 4; b++) {
        qkv_naive<0><<<dim3(27, 512), 256, 0, stream>>>(kw, kb_, x, ab, kbuf, 6912, 0, b, flag);
        qkv_naive<0><<<dim3(27, 512), 256, 0, stream>>>(vw, vb_, x, ab, vbuf, 6912, 0, b, flag);
        qkv_naive<1><<<dim3(9, 512), 256, 0, stream>>>(qw, qb_, x, ab, qbuf, 2304, 2304, b, flag);
        s_naive<<<dim3(27, 2304), 256, 0, stream>>>(qbuf, kbuf, sbuf);
        softmax_k<<<2304, 256, 0, stream>>>(sbuf);
        o_naive<<<dim3(576, 512), 256, 0, stream>>>(vbuf, sbuf, obuf);
        proj_naive<<<dim3(9, 512), 256, 0, stream>>>(pw, pb_, obuf, qbuf, out, b, flag);
    }
}

// Round 10
// 1291.718 us; speedup vs baseline: 24.6184x; 24.6184x over previous
//
#include <hip/hip_runtime.h>

typedef unsigned short u16;
typedef __attribute__((ext_vector_type(8))) short short8;
typedef __attribute__((ext_vector_type(4))) float f32x4;

__device__ __forceinline__ float bf2f(u16 h) {
    union { unsigned int u; float f; } v; v.u = ((unsigned int)h) << 16; return v.f;
}
__device__ __forceinline__ u16 f2bf(float f) {
    union { float f; unsigned int u; } v; v.f = f;
    unsigned int r = v.u + 0x7fffu + ((v.u >> 16) & 1u);
    return (u16)(r >> 16);
}

__device__ __forceinline__ float waveSum(float v) {
#pragma unroll
    for (int o = 32; o > 0; o >>= 1) v += __shfl_down(v, o);
    return v;
}
__device__ __forceinline__ float waveMax(float v) {
#pragma unroll
    for (int o = 32; o > 0; o >>= 1) v = fmaxf(v, __shfl_down(v, o));
    return v;
}
__device__ __forceinline__ int waveSumI(int v) {
#pragma unroll
    for (int o = 32; o > 0; o >>= 1) v += __shfl_down(v, o);
    return v;
}

// ---------------- dtype detection: flag=1 if inputs bf16, 0 if f32 ----------------
__global__ __launch_bounds__(256) void detect_k(const u16* __restrict__ x, int* __restrict__ flag) {
    __shared__ int cnt[4];
    int c = 0;
    for (int i = threadIdx.x; i < 8192; i += 256) {
        u16 e = x[i * 2];
        int ex = (e >> 7) & 0xFF;
        c += (ex == 0 || (ex >= 100 && ex <= 150)) ? 1 : 0;
    }
    c = waveSumI(c);
    if ((threadIdx.x & 63) == 0) cnt[threadIdx.x >> 6] = c;
    __syncthreads();
    if (threadIdx.x == 0)
        flag[0] = ((cnt[0] + cnt[1] + cnt[2] + cnt[3]) > 4915) ? 1 : 0;
}

// ---------------- convert input -> bf16 ws buffer (copy or downcast) ----------------
__global__ __launch_bounds__(256) void conv_k(const void* __restrict__ src, u16* __restrict__ dst,
                                              int n8, const int* __restrict__ flag) {
    int i = blockIdx.x * 256 + threadIdx.x;
    if (i >= n8) return;
    if (flag[0]) {
        ((int4*)dst)[i] = ((const int4*)src)[i];
    } else {
        const float* f = (const float*)src + (size_t)i * 8;
        union { int4 v4; u16 o[8]; } tv;
#pragma unroll
        for (int j = 0; j < 8; j++) tv.o[j] = f2bf(f[j]);
        ((int4*)dst)[i] = tv.v4;
    }
}

// ---------------- GroupNorm stats on bf16 xb ----------------
__global__ __launch_bounds__(256) void gn_stats(const u16* __restrict__ x, float* __restrict__ stat) {
    __shared__ float red[8];
    const int gg = blockIdx.y, chunk = blockIdx.x;
    const int b = gg >> 2, g = gg & 3;
    float s = 0.f, s2 = 0.f;
    for (int pp = 0; pp < 48; pp++) {
        int p = chunk * 48 + pp;
        int t = p >> 7, cc = p & 127;
        const u16* rowp = x + (size_t)((t * 4 + b) * 512 + g * 128 + cc) * 2304;
        for (int vi = threadIdx.x; vi < 288; vi += 256) {
            union { int4 v4; u16 u[8]; } tv;
            tv.v4 = *(const int4*)(rowp + vi * 8);
#pragma unroll
            for (int j = 0; j < 8; j++) { float f = bf2f(tv.u[j]); s += f; s2 += f * f; }
        }
    }
    s = waveSum(s); s2 = waveSum(s2);
    int wid = threadIdx.x >> 6;
    if ((threadIdx.x & 63) == 0) { red[wid] = s; red[wid + 4] = s2; }
    __syncthreads();
    if (threadIdx.x == 0) {
        atomicAdd(&stat[gg], red[0] + red[1] + red[2] + red[3]);
        atomicAdd(&stat[16 + gg], red[4] + red[5] + red[6] + red[7]);
    }
}

// ---------------- per-(b,c) affine ----------------
__global__ void gn_ab(const float* __restrict__ stat, const u16* __restrict__ scale,
                      const u16* __restrict__ bias, float2* __restrict__ ab) {
    int idx = blockIdx.x * 256 + threadIdx.x;
    int b = idx >> 9, c = idx & 511, g = c >> 7, gg = b * 4 + g;
    const float invN = 1.f / 884736.f;
    float mean = stat[gg] * invN;
    float var  = stat[16 + gg] * invN - mean * mean;
    float rstd = rsqrtf(var + 1e-6f);
    float a = rstd * bf2f(scale[c]);
    ab[idx] = make_float2(a, bf2f(bias[c]) - mean * a);
}

// ---------------- generic MFMA GEMM (function cross-validated R4==R5) ----------------
// D[i][j] = alpha * sum_k A[i][k]*B[k][j]  (+bias[i]) (+skip[i][j]); out bf16 or f32.
// AMODE 0: A[i][k]; 1: A[k][i].  BMODE 0: B[k][j]; 1: B[j][k]; 2: x + fused GN affine.
// EPI bit0: +bias[i]; bit1: +skip.  F32OUT: C is float* else u16*.
template<int WR, int WC, int TI, int TJ, int AMODE, int BMODE, int EPI, int F32OUT>
__global__ __launch_bounds__(256)
void gemm_k(const u16* __restrict__ A, const u16* __restrict__ B, void* __restrict__ C,
            const u16* __restrict__ bias, const u16* __restrict__ skip,
            const float2* __restrict__ ab,
            int lda, int ldb, int ldc,
            int K, float alpha, int m_off, int b0) {
    constexpr int BM = WR * TI * 16;
    constexpr int BN = WC * TJ * 16;
    constexpr int LDS_S = 36;
    __shared__ alignas(16) u16 As[BM][LDS_S];
    __shared__ alignas(16) u16 Bs[BN][LDS_S];

    const int tid = threadIdx.x;
    const int i0b = blockIdx.y * BM;
    const int j0b = blockIdx.x * BN;

    const u16* Ap = A;
    const u16* Bp;
    const float2* abp = nullptr;
    int yx0 = 0;
    if (BMODE == 2) {
        int m_tile = j0b + m_off;
        int t = m_tile / 2304;
        yx0 = m_tile - t * 2304;
        Bp = B + (size_t)((t * 4 + b0) * 512) * 2304;
        abp = ab + b0 * 512;
    } else {
        Bp = B;
    }

    const int wave = tid >> 6;
    const int lane = tid & 63;
    const int wr = wave / WC;
    const int wc = wave % WC;
    const int lrow = lane & 15;
    const int quad = lane >> 4;

    f32x4 acc[TI][TJ] = {};

    for (int k0 = 0; k0 < K; k0 += 32) {
        __syncthreads();
        if (AMODE == 0) {
            constexpr int NV = (BM * 32 / 8) / 256;
#pragma unroll
            for (int v = 0; v < NV; v++) {
                int vid = tid + v * 256;
                int i = vid >> 2, kk = (vid & 3) * 8;
                union { int4 v4; unsigned long long u[2]; } tv;
                tv.v4 = *(const int4*)(Ap + (size_t)(i0b + i) * lda + (k0 + kk));
                *(unsigned long long*)(&As[i][kk])     = tv.u[0];
                *(unsigned long long*)(&As[i][kk + 4]) = tv.u[1];
            }
        } else {
            constexpr int NV = (BM * 32 / 8) / 256;
            constexpr int IG = BM / 8;
#pragma unroll
            for (int v = 0; v < NV; v++) {
                int vid = tid + v * 256;
                int k = vid / IG, ib = (vid % IG) * 8;
                union { int4 v4; u16 s[8]; } tv;
                tv.v4 = *(const int4*)(Ap + (size_t)(k0 + k) * lda + (i0b + ib));
#pragma unroll
                for (int j = 0; j < 8; j++) As[ib + j][k] = tv.s[j];
            }
        }
        if (BMODE == 1) {
            constexpr int NV = (BN * 32 / 8) / 256;
#pragma unroll
            for (int v = 0; v < NV; v++) {
                int vid = tid + v * 256;
                int j = vid >> 2, kk = (vid & 3) * 8;
                union { int4 v4; unsigned long long u[2]; } tv;
                tv.v4 = *(const int4*)(Bp + (size_t)(j0b + j) * ldb + (k0 + kk));
                *(unsigned long long*)(&Bs[j][kk])     = tv.u[0];
                *(unsigned long long*)(&Bs[j][kk + 4]) = tv.u[1];
            }
        } else {
            constexpr int NV = (BN * 32 / 8) / 256;
            constexpr int JG = BN / 8;
#pragma unroll
            for (int v = 0; v < NV; v++) {
                int vid = tid + v * 256;
                int k = vid / JG, jb = (vid % JG) * 8;
                if (BMODE == 0) {
                    union { int4 v4; u16 s[8]; } tv;
                    tv.v4 = *(const int4*)(Bp + (size_t)(k0 + k) * ldb + (j0b + jb));
#pragma unroll
                    for (int j = 0; j < 8; j++) Bs[jb + j][k] = tv.s[j];
                } else {
                    union { int4 v4; u16 s[8]; } tv;
                    tv.v4 = *(const int4*)(Bp + (size_t)(k0 + k) * 2304 + (yx0 + jb));
                    float2 amb = abp[k0 + k];
#pragma unroll
                    for (int j = 0; j < 8; j++)
                        Bs[jb + j][k] = f2bf(bf2f(tv.s[j]) * amb.x + amb.y);
                }
            }
        }
        __syncthreads();
        union { short8 v; unsigned long long u[2]; } fa[TI], fb[TJ];
#pragma unroll
        for (int ri = 0; ri < TI; ri++) {
            int r = wr * TI * 16 + ri * 16 + lrow;
            fa[ri].u[0] = *(const unsigned long long*)(&As[r][quad * 8]);
            fa[ri].u[1] = *(const unsigned long long*)(&As[r][quad * 8 + 4]);
        }
#pragma unroll
        for (int cj = 0; cj < TJ; cj++) {
            int cc2 = wc * TJ * 16 + cj * 16 + lrow;
            fb[cj].u[0] = *(const unsigned long long*)(&Bs[cc2][quad * 8]);
            fb[cj].u[1] = *(const unsigned long long*)(&Bs[cc2][quad * 8 + 4]);
        }
#pragma unroll
        for (int ri = 0; ri < TI; ri++)
#pragma unroll
            for (int cj = 0; cj < TJ; cj++)
                acc[ri][cj] = __builtin_amdgcn_mfma_f32_16x16x32_bf16(
                    fa[ri].v, fb[cj].v, acc[ri][cj], 0, 0, 0);
    }

#pragma unroll
    for (int ri = 0; ri < TI; ri++) {
#pragma unroll
        for (int reg = 0; reg < 4; reg++) {
            int gi = i0b + wr * TI * 16 + ri * 16 + quad * 4 + reg;
            float bv = (EPI & 1) ? bf2f(bias[gi]) : 0.f;
#pragma unroll
            for (int cj = 0; cj < TJ; cj++) {
                int gj = j0b + wc * TJ * 16 + cj * 16 + lrow;
                float v = acc[ri][cj][reg] * alpha + bv;
                if (EPI & 2) v += bf2f(skip[(size_t)gi * ldc + gj]);
                if (F32OUT) ((float*)C)[(size_t)gi * ldc + gj] = v;
                else        ((u16*)C)[(size_t)gi * ldc + gj] = f2bf(v);
            }
        }
    }
}

// ---------------- row softmax over m=6912, bf16 in-place ----------------
__global__ __launch_bounds__(256) void softmax_k(u16* __restrict__ sb) {
    __shared__ float row[6912];
    __shared__ float red[8];
    u16* p = sb + (size_t)blockIdx.x * 6912;
    const int tid = threadIdx.x;
    float mx = -3.0e38f;
    for (int vi = tid; vi < 864; vi += 256) {
        union { int4 v4; u16 u[8]; } tv;
        tv.v4 = *(const int4*)(p + vi * 8);
#pragma unroll
        for (int j = 0; j < 8; j++) { float f = bf2f(tv.u[j]); row[vi * 8 + j] = f; mx = fmaxf(mx, f); }
    }
    mx = waveMax(mx);
    if ((tid & 63) == 0) red[tid >> 6] = mx;
    __syncthreads();
    mx = fmaxf(fmaxf(red[0], red[1]), fmaxf(red[2], red[3]));
    __syncthreads();
    float sum = 0.f;
    for (int i = tid; i < 6912; i += 256) {
        float e = __expf(row[i] - mx);
        row[i] = e; sum += e;
    }
    sum = waveSum(sum);
    if ((tid & 63) == 0) red[4 + (tid >> 6)] = sum;
    __syncthreads();
    float inv = 1.f / (red[4] + red[5] + red[6] + red[7]);
    for (int vi = tid; vi < 864; vi += 256) {
        union { int4 v4; u16 u[8]; } tv;
#pragma unroll
        for (int j = 0; j < 8; j++) tv.u[j] = f2bf(row[vi * 8 + j] * inv);
        *(int4*)(p + vi * 8) = tv.v4;
    }
}

extern "C" void kernel_launch(void* const* d_in, const int* in_sizes, int n_in,
                              void* d_out, int out_size, void* d_ws, size_t ws_size,
                              hipStream_t stream) {
    float* out = (float*)d_out;   // output dtype is FLOAT32 (verified R9)

    // workspace layout (~78 MiB, same footprint R3/R4 ran cleanly with)
    char* w = (char*)d_ws;
    int*    flag = (int*)w;     w += 256;
    float*  stat = (float*)w;   w += 256;
    float2* ab   = (float2*)w;  w += 2048 * sizeof(float2);
    u16* xb  = (u16*)w;  w += (size_t)14155776 * 2;           // 12*512*48*48
    u16* wgt[4];
    for (int i = 0; i < 4; i++) { wgt[i] = (u16*)w; w += (size_t)262144 * 2; }
    u16* vec[6];
    for (int i = 0; i < 6; i++) { vec[i] = (u16*)w; w += 1024; }
    u16* qbuf = (u16*)w;  w += (size_t)512 * 2304 * 2;
    u16* kbuf = (u16*)w;  w += (size_t)512 * 6912 * 2;
    u16* vbuf = (u16*)w;  w += (size_t)512 * 6912 * 2;
    u16* obuf = (u16*)w;  w += (size_t)512 * 2304 * 2;
    u16* sbuf = (u16*)w;  // 2304*6912 bf16 = 30.4 MiB

    detect_k<<<1, 256, 0, stream>>>((const u16*)d_in[0], flag);
    conv_k<<<6912, 256, 0, stream>>>(d_in[0], xb, 1769472, flag);
    conv_k<<<128, 256, 0, stream>>>(d_in[3], wgt[0], 32768, flag);
    conv_k<<<128, 256, 0, stream>>>(d_in[5], wgt[1], 32768, flag);
    conv_k<<<128, 256, 0, stream>>>(d_in[7], wgt[2], 32768, flag);
    conv_k<<<128, 256, 0, stream>>>(d_in[9], wgt[3], 32768, flag);
    conv_k<<<1, 256, 0, stream>>>(d_in[1],  vec[0], 64, flag);
    conv_k<<<1, 256, 0, stream>>>(d_in[2],  vec[1], 64, flag);
    conv_k<<<1, 256, 0, stream>>>(d_in[4],  vec[2], 64, flag);
    conv_k<<<1, 256, 0, stream>>>(d_in[6],  vec[3], 64, flag);
    conv_k<<<1, 256, 0, stream>>>(d_in[8],  vec[4], 64, flag);
    conv_k<<<1, 256, 0, stream>>>(d_in[10], vec[5], 64, flag);

    hipMemsetAsync(stat, 0, 32 * sizeof(float), stream);
    gn_stats<<<dim3(8, 16), 256, 0, stream>>>(xb, stat);
    gn_ab<<<8, 256, 0, stream>>>(stat, vec[0], vec[1], ab);

    const float rs = 0.044194173824159216f;  // 1/sqrt(512)

    for (int b = 0; b < 4; b++) {
        // K = kw @ hn : [512 x 6912]
        gemm_k<2, 2, 4, 4, 0, 2, 1, 0><<<dim3(54, 4, 1), 256, 0, stream>>>(
            wgt[1], xb, kbuf, vec[3], nullptr, ab, 512, 0, 6912, 512, 1.f, 0, b);
        // V
        gemm_k<2, 2, 4, 4, 0, 2, 1, 0><<<dim3(54, 4, 1), 256, 0, stream>>>(
            wgt[2], xb, vbuf, vec[4], nullptr, ab, 512, 0, 6912, 512, 1.f, 0, b);
        // Q (frame 1): m_off = 2304
        gemm_k<2, 2, 4, 4, 0, 2, 1, 0><<<dim3(18, 4, 1), 256, 0, stream>>>(
            wgt[0], xb, qbuf, vec[2], nullptr, ab, 512, 0, 2304, 512, 1.f, 2304, b);
        // S[p][m] = q^T k * rs
        gemm_k<2, 2, 4, 4, 1, 0, 0, 0><<<dim3(54, 18, 1), 256, 0, stream>>>(
            qbuf, kbuf, sbuf, nullptr, nullptr, nullptr, 2304, 6912, 6912, 512, rs, 0, b);
        softmax_k<<<2304, 256, 0, stream>>>(sbuf);
        // O[c][p] = v @ attn^T : 64x64 tiles, K=6912
        gemm_k<1, 4, 4, 1, 0, 1, 0, 0><<<dim3(36, 8, 1), 256, 0, stream>>>(
            vbuf, sbuf, obuf, nullptr, nullptr, nullptr, 6912, 6912, 2304, 6912, 1.f, 0, b);
        // out = pw @ O + pb + skip(q), FLOAT32 output
        gemm_k<2, 2, 4, 2, 0, 0, 3, 1><<<dim3(36, 4, 1), 256, 0, stream>>>(
            wgt[3], obuf, out + (size_t)b * 512 * 2304, vec[5], qbuf, nullptr,
            512, 2304, 2304, 512, 1.f, 0, b);
    }
}

// Round 11
// 735.020 us; speedup vs baseline: 43.2642x; 1.7574x over previous
//
#include <hip/hip_runtime.h>

typedef unsigned short u16;
typedef unsigned long long u64;
typedef __attribute__((ext_vector_type(8))) short short8;
typedef __attribute__((ext_vector_type(4))) float f32x4;

__device__ __forceinline__ float bf2f(u16 h) {
    union { unsigned int u; float f; } v; v.u = ((unsigned int)h) << 16; return v.f;
}
__device__ __forceinline__ u16 f2bf(float f) {
    union { float f; unsigned int u; } v; v.f = f;
    unsigned int r = v.u + 0x7fffu + ((v.u >> 16) & 1u);
    return (u16)(r >> 16);
}

__device__ __forceinline__ float waveSum(float v) {
#pragma unroll
    for (int o = 32; o > 0; o >>= 1) v += __shfl_down(v, o);
    return v;
}
__device__ __forceinline__ float waveMax(float v) {
#pragma unroll
    for (int o = 32; o > 0; o >>= 1) v = fmaxf(v, __shfl_down(v, o));
    return v;
}
__device__ __forceinline__ int waveSumI(int v) {
#pragma unroll
    for (int o = 32; o > 0; o >>= 1) v += __shfl_down(v, o);
    return v;
}

// ---------------- dtype detection: flag=1 if inputs bf16, 0 if f32 ----------------
__global__ __launch_bounds__(256) void detect_k(const u16* __restrict__ x, int* __restrict__ flag) {
    __shared__ int cnt[4];
    int c = 0;
    for (int i = threadIdx.x; i < 8192; i += 256) {
        u16 e = x[i * 2];
        int ex = (e >> 7) & 0xFF;
        c += (ex == 0 || (ex >= 100 && ex <= 150)) ? 1 : 0;
    }
    c = waveSumI(c);
    if ((threadIdx.x & 63) == 0) cnt[threadIdx.x >> 6] = c;
    __syncthreads();
    if (threadIdx.x == 0)
        flag[0] = ((cnt[0] + cnt[1] + cnt[2] + cnt[3]) > 4915) ? 1 : 0;
}

// ---------------- convert input -> bf16 (copy or downcast) ----------------
__global__ __launch_bounds__(256) void conv_k(const void* __restrict__ src, u16* __restrict__ dst,
                                              int n8, const int* __restrict__ flag) {
    int i = blockIdx.x * 256 + threadIdx.x;
    if (i >= n8) return;
    if (flag[0]) {
        ((int4*)dst)[i] = ((const int4*)src)[i];
    } else {
        const float* f = (const float*)src + (size_t)i * 8;
        union { int4 v4; u16 o[8]; } tv;
#pragma unroll
        for (int j = 0; j < 8; j++) tv.o[j] = f2bf(f[j]);
        ((int4*)dst)[i] = tv.v4;
    }
}

// fused 4-weight convert: grid (128, 4)
__global__ __launch_bounds__(256) void conv_w4(const void* s0, const void* s1, const void* s2, const void* s3,
                                               u16* __restrict__ dst, const int* __restrict__ flag) {
    int i = blockIdx.x * 256 + threadIdx.x;           // < 32768 int4 groups
    int w = blockIdx.y;
    const void* s = w == 0 ? s0 : w == 1 ? s1 : w == 2 ? s2 : s3;
    u16* d = dst + (size_t)w * 262144;
    if (flag[0]) {
        ((int4*)d)[i] = ((const int4*)s)[i];
    } else {
        const float* f = (const float*)s + (size_t)i * 8;
        union { int4 v4; u16 o[8]; } tv;
#pragma unroll
        for (int j = 0; j < 8; j++) tv.o[j] = f2bf(f[j]);
        ((int4*)d)[i] = tv.v4;
    }
}

// fused 6-vector convert into contiguous vecb (6 x 512)
__global__ __launch_bounds__(256) void conv_v6(const void* s0, const void* s1, const void* s2,
                                               const void* s3, const void* s4, const void* s5,
                                               u16* __restrict__ dst, const int* __restrict__ flag) {
    for (int i = threadIdx.x; i < 384; i += 256) {
        int seg = i >> 6, off = i & 63;
        const void* s = seg == 0 ? s0 : seg == 1 ? s1 : seg == 2 ? s2 : seg == 3 ? s3 : seg == 4 ? s4 : s5;
        u16* d = dst + (size_t)seg * 512;
        if (flag[0]) {
            ((int4*)d)[off] = ((const int4*)s)[off];
        } else {
            const float* f = (const float*)s + (size_t)off * 8;
            union { int4 v4; u16 o[8]; } tv;
#pragma unroll
            for (int j = 0; j < 8; j++) tv.o[j] = f2bf(f[j]);
            ((int4*)d)[off] = tv.v4;
        }
    }
}

// ---------------- GroupNorm stats on bf16 xb: grid (32, 16) ----------------
__global__ __launch_bounds__(256) void gn_stats(const u16* __restrict__ x, float* __restrict__ stat) {
    __shared__ float red[8];
    const int gg = blockIdx.y, chunk = blockIdx.x;
    const int b = gg >> 2, g = gg & 3;
    float s = 0.f, s2 = 0.f;
    for (int pp = 0; pp < 12; pp++) {
        int p = chunk * 12 + pp;
        int t = p >> 7, cc = p & 127;
        const u16* rowp = x + (size_t)((t * 4 + b) * 512 + g * 128 + cc) * 2304;
        for (int vi = threadIdx.x; vi < 288; vi += 256) {
            union { int4 v4; u16 u[8]; } tv;
            tv.v4 = *(const int4*)(rowp + vi * 8);
#pragma unroll
            for (int j = 0; j < 8; j++) { float f = bf2f(tv.u[j]); s += f; s2 += f * f; }
        }
    }
    s = waveSum(s); s2 = waveSum(s2);
    int wid = threadIdx.x >> 6;
    if ((threadIdx.x & 63) == 0) { red[wid] = s; red[wid + 4] = s2; }
    __syncthreads();
    if (threadIdx.x == 0) {
        atomicAdd(&stat[gg], red[0] + red[1] + red[2] + red[3]);
        atomicAdd(&stat[16 + gg], red[4] + red[5] + red[6] + red[7]);
    }
}

// ---------------- per-(b,c) affine ----------------
__global__ void gn_ab(const float* __restrict__ stat, const u16* __restrict__ scale,
                      const u16* __restrict__ bias, float2* __restrict__ ab) {
    int idx = blockIdx.x * 256 + threadIdx.x;
    int b = idx >> 9, c = idx & 511, g = c >> 7, gg = b * 4 + g;
    const float invN = 1.f / 884736.f;
    float mean = stat[gg] * invN;
    float var  = stat[16 + gg] * invN - mean * mean;
    float rstd = rsqrtf(var + 1e-6f);
    float a = rstd * bf2f(scale[c]);
    ab[idx] = make_float2(a, bf2f(bias[c]) - mean * a);
}

// ---------------- bf16 transpose: src [512][cols] -> dst [cols][512]; grid (cols/64, 8, z) ----
__global__ __launch_bounds__(256) void tr_k(const u16* __restrict__ src, u16* __restrict__ dst,
                                            int cols, long zsS, long zsD) {
    __shared__ u16 t[64][72];
    const u16* s = src + (size_t)blockIdx.z * zsS;
    u16* d = dst + (size_t)blockIdx.z * zsD;
    int c0 = blockIdx.x * 64;   // col tile (n-dim)
    int r0 = blockIdx.y * 64;   // row tile (c-dim)
    int tid = threadIdx.x;
#pragma unroll
    for (int p = 0; p < 4; p++) {
        int r = p * 16 + (tid >> 4);
        int c4 = (tid & 15) * 4;
        u64 v = *(const u64*)(s + (size_t)(r0 + r) * cols + c0 + c4);
        *(u64*)(&t[r][c4]) = v;
    }
    __syncthreads();
#pragma unroll
    for (int p = 0; p < 2; p++) {
        int n = p * 32 + (tid >> 3);
        int c8 = (tid & 7) * 8;
        union { int4 v4; u16 o[8]; } tv;
#pragma unroll
        for (int j = 0; j < 8; j++) tv.o[j] = t[c8 + j][n];
        *(int4*)(d + (size_t)(c0 + n) * 512 + r0 + c8) = tv.v4;
    }
}

// ---------------- reduce 6 f32 split-K partials [c][n] -> bf16 transposed [n][c] -----------
__global__ __launch_bounds__(256) void reduce6t(const float* __restrict__ part, u16* __restrict__ outT) {
    __shared__ u16 t[64][72];
    const long PS = (long)512 * 2304;
    int n0 = blockIdx.x * 64, c0 = blockIdx.y * 64;
    int tid = threadIdx.x;
#pragma unroll
    for (int p = 0; p < 4; p++) {
        int c = p * 16 + (tid >> 4);
        int n4 = (tid & 15) * 4;
        float4 s = make_float4(0.f, 0.f, 0.f, 0.f);
#pragma unroll
        for (int q = 0; q < 6; q++) {
            float4 v = *(const float4*)(part + q * PS + (size_t)(c0 + c) * 2304 + n0 + n4);
            s.x += v.x; s.y += v.y; s.z += v.z; s.w += v.w;
        }
        t[c][n4] = f2bf(s.x); t[c][n4 + 1] = f2bf(s.y); t[c][n4 + 2] = f2bf(s.z); t[c][n4 + 3] = f2bf(s.w);
    }
    __syncthreads();
#pragma unroll
    for (int p = 0; p < 2; p++) {
        int n = p * 32 + (tid >> 3);
        int c8 = (tid & 7) * 8;
        union { int4 v4; u16 o[8]; } tv;
#pragma unroll
        for (int j = 0; j < 8; j++) tv.o[j] = t[c8 + j][n];
        *(int4*)(outT + (size_t)(n0 + n) * 512 + c0 + c8) = tv.v4;
    }
}

// ---------------- generic MFMA GEMM ----------------
// D[i][j] = alpha*sum_k A[i][k]B[k][j] (+bias[i]) (+skip); bf16 or f32 out.
// AMODE 0: A[i][k]; 1: A[k][i].  BMODE 0: B[k][j]; 1: B[j][k]; 2: x + fused GN affine.
// EPI bit0 +bias, bit1 +skip. F32OUT: C float*. SPLITK: blockIdx.z = K-chunk (len K).
// z-strides (elements): aZS, bZS, cZS, sZS.
template<int WR, int WC, int TI, int TJ, int AMODE, int BMODE, int EPI, int F32OUT, int SPLITK>
__global__ __launch_bounds__(256)
void gemm_k(const u16* __restrict__ A, const u16* __restrict__ B, void* __restrict__ Cv,
            const u16* __restrict__ bias, const u16* __restrict__ skip,
            const float2* __restrict__ ab,
            int lda, int ldb, int ldc,
            int K, float alpha, int m_off, int b0,
            long aZS, long bZS, long cZS, long sZS) {
    constexpr int BM = WR * TI * 16;
    constexpr int BN = WC * TJ * 16;
    constexpr int LDS_S = 44;   // 88 B stride: 8B-aligned b64, <=2-way bank alias (free)
    __shared__ alignas(16) u16 As[BM][LDS_S];
    __shared__ alignas(16) u16 Bs[BN][LDS_S];

    const int tid = threadIdx.x;
    const int z = blockIdx.z;
    const int i0b = blockIdx.y * BM;
    const int j0b = blockIdx.x * BN;
    const int kstart = SPLITK ? z * K : 0;

    const u16* Ap = A + (size_t)z * aZS;
    const u16* Bp;
    const float2* abp = nullptr;
    int yx0 = 0;
    if (BMODE == 2) {
        int b = b0 + (SPLITK ? 0 : z);
        int m_tile = j0b + m_off;
        int t = m_tile / 2304;
        yx0 = m_tile - t * 2304;
        Bp = B + (size_t)((t * 4 + b) * 512) * 2304;
        abp = ab + b * 512;
    } else {
        Bp = B + (size_t)z * bZS;
    }
    const u16* Sp = (EPI & 2) ? (skip + (size_t)z * sZS) : nullptr;
    float* Cf = (float*)Cv + (size_t)z * (F32OUT ? cZS : 0);
    u16*   Ch = (u16*)Cv   + (size_t)z * (F32OUT ? 0 : cZS);

    const int wave = tid >> 6;
    const int lane = tid & 63;
    const int wr = wave / WC;
    const int wc = wave % WC;
    const int lrow = lane & 15;
    const int quad = lane >> 4;

    f32x4 acc[TI][TJ] = {};

    for (int k0 = kstart; k0 < kstart + K; k0 += 32) {
        __syncthreads();
        if (AMODE == 0) {
            constexpr int NV = (BM * 32 / 8) / 256;
#pragma unroll
            for (int v = 0; v < NV; v++) {
                int vid = tid + v * 256;
                int i = vid >> 2, kk = (vid & 3) * 8;
                union { int4 v4; u64 u[2]; } tv;
                tv.v4 = *(const int4*)(Ap + (size_t)(i0b + i) * lda + (k0 + kk));
                *(u64*)(&As[i][kk])     = tv.u[0];
                *(u64*)(&As[i][kk + 4]) = tv.u[1];
            }
        } else {
            constexpr int NV = (BM * 32 / 8) / 256;
            constexpr int IG = BM / 8;
#pragma unroll
            for (int v = 0; v < NV; v++) {
                int vid = tid + v * 256;
                int k = vid / IG, ib = (vid % IG) * 8;
                union { int4 v4; u16 s[8]; } tv;
                tv.v4 = *(const int4*)(Ap + (size_t)(k0 + k) * lda + (i0b + ib));
#pragma unroll
                for (int j = 0; j < 8; j++) As[ib + j][k] = tv.s[j];
            }
        }
        if (BMODE == 1) {
            constexpr int NV = (BN * 32 / 8) / 256;
#pragma unroll
            for (int v = 0; v < NV; v++) {
                int vid = tid + v * 256;
                int j = vid >> 2, kk = (vid & 3) * 8;
                union { int4 v4; u64 u[2]; } tv;
                tv.v4 = *(const int4*)(Bp + (size_t)(j0b + j) * ldb + (k0 + kk));
                *(u64*)(&Bs[j][kk])     = tv.u[0];
                *(u64*)(&Bs[j][kk + 4]) = tv.u[1];
            }
        } else {
            constexpr int NV = (BN * 32 / 8) / 256;
            constexpr int JG = BN / 8;
#pragma unroll
            for (int v = 0; v < NV; v++) {
                int vid = tid + v * 256;
                int k = vid / JG, jb = (vid % JG) * 8;
                if (BMODE == 0) {
                    union { int4 v4; u16 s[8]; } tv;
                    tv.v4 = *(const int4*)(Bp + (size_t)(k0 + k) * ldb + (j0b + jb));
#pragma unroll
                    for (int j = 0; j < 8; j++) Bs[jb + j][k] = tv.s[j];
                } else {
                    union { int4 v4; u16 s[8]; } tv;
                    tv.v4 = *(const int4*)(Bp + (size_t)(k0 + k) * 2304 + (yx0 + jb));
                    float2 amb = abp[k0 + k];
#pragma unroll
                    for (int j = 0; j < 8; j++)
                        Bs[jb + j][k] = f2bf(bf2f(tv.s[j]) * amb.x + amb.y);
                }
            }
        }
        __syncthreads();
        union { short8 v; u64 u[2]; } fa[TI], fb[TJ];
#pragma unroll
        for (int ri = 0; ri < TI; ri++) {
            int r = wr * TI * 16 + ri * 16 + lrow;
            fa[ri].u[0] = *(const u64*)(&As[r][quad * 8]);
            fa[ri].u[1] = *(const u64*)(&As[r][quad * 8 + 4]);
        }
#pragma unroll
        for (int cj = 0; cj < TJ; cj++) {
            int cc2 = wc * TJ * 16 + cj * 16 + lrow;
            fb[cj].u[0] = *(const u64*)(&Bs[cc2][quad * 8]);
            fb[cj].u[1] = *(const u64*)(&Bs[cc2][quad * 8 + 4]);
        }
#pragma unroll
        for (int ri = 0; ri < TI; ri++)
#pragma unroll
            for (int cj = 0; cj < TJ; cj++)
                acc[ri][cj] = __builtin_amdgcn_mfma_f32_16x16x32_bf16(
                    fa[ri].v, fb[cj].v, acc[ri][cj], 0, 0, 0);
    }

#pragma unroll
    for (int ri = 0; ri < TI; ri++) {
#pragma unroll
        for (int reg = 0; reg < 4; reg++) {
            int gi = i0b + wr * TI * 16 + ri * 16 + quad * 4 + reg;
            float bv = (EPI & 1) ? bf2f(bias[gi]) : 0.f;
#pragma unroll
            for (int cj = 0; cj < TJ; cj++) {
                int gj = j0b + wc * TJ * 16 + cj * 16 + lrow;
                float v = acc[ri][cj][reg] * alpha + bv;
                if (EPI & 2) v += bf2f(Sp[(size_t)gi * ldc + gj]);
                if (F32OUT) Cf[(size_t)gi * ldc + gj] = v;
                else        Ch[(size_t)gi * ldc + gj] = f2bf(v);
            }
        }
    }
}

// ---------------- row softmax over m=6912, bf16 in-place; grid (2304, z) ----------------
__global__ __launch_bounds__(256) void softmax_k(u16* __restrict__ sb, long zs) {
    __shared__ float row[6912];
    __shared__ float red[8];
    u16* p = sb + (size_t)blockIdx.y * zs + (size_t)blockIdx.x * 6912;
    const int tid = threadIdx.x;
    float mx = -3.0e38f;
    for (int vi = tid; vi < 864; vi += 256) {
        union { int4 v4; u16 u[8]; } tv;
        tv.v4 = *(const int4*)(p + vi * 8);
#pragma unroll
        for (int j = 0; j < 8; j++) { float f = bf2f(tv.u[j]); row[vi * 8 + j] = f; mx = fmaxf(mx, f); }
    }
    mx = waveMax(mx);
    if ((tid & 63) == 0) red[tid >> 6] = mx;
    __syncthreads();
    mx = fmaxf(fmaxf(red[0], red[1]), fmaxf(red[2], red[3]));
    __syncthreads();
    float sum = 0.f;
    for (int i = tid; i < 6912; i += 256) {
        float e = __expf(row[i] - mx);
        row[i] = e; sum += e;
    }
    sum = waveSum(sum);
    if ((tid & 63) == 0) red[4 + (tid >> 6)] = sum;
    __syncthreads();
    float inv = 1.f / (red[4] + red[5] + red[6] + red[7]);
    for (int vi = tid; vi < 864; vi += 256) {
        union { int4 v4; u16 u[8]; } tv;
#pragma unroll
        for (int j = 0; j < 8; j++) tv.u[j] = f2bf(row[vi * 8 + j] * inv);
        *(int4*)(p + vi * 8) = tv.v4;
    }
}

extern "C" void kernel_launch(void* const* d_in, const int* in_sizes, int n_in,
                              void* d_out, int out_size, void* d_ws, size_t ws_size,
                              hipStream_t stream) {
    float* out = (float*)d_out;   // f32 output (verified R9/R10)

    const long QS = (long)512 * 2304;    // 1,179,648
    const long KS = (long)512 * 6912;    // 3,538,944
    const long SS = (long)2304 * 6912;   // 15,925,248
    const long PS = (long)512 * 2304;    // f32 partial stride
    const float rs = 0.044194173824159216f;

    // mode select by workspace size (lite == proven R10 schedule)
    int nb = 0;
    if      (ws_size >= 275000000ull) nb = 4;
    else if (ws_size >= 185000000ull) nb = 2;
    else if (ws_size >= 125000000ull) nb = 1;

    char* w = (char*)d_ws;
    int*    flag = (int*)w;     w += 256;
    float*  stat = (float*)w;   w += 256;
    float2* ab   = (float2*)w;  w += 2048 * sizeof(float2);
    u16* xb = (u16*)w;  w += (size_t)14155776 * 2;
    u16* wgt = (u16*)w; w += (size_t)4 * 262144 * 2;
    u16* vecb = (u16*)w; w += 8192;

    // common preamble
    detect_k<<<1, 256, 0, stream>>>((const u16*)d_in[0], flag);
    conv_k<<<6912, 256, 0, stream>>>(d_in[0], xb, 1769472, flag);
    conv_w4<<<dim3(128, 4), 256, 0, stream>>>(d_in[3], d_in[5], d_in[7], d_in[9], wgt, flag);
    conv_v6<<<1, 256, 0, stream>>>(d_in[1], d_in[2], d_in[4], d_in[6], d_in[8], d_in[10], vecb, flag);
    hipMemsetAsync(stat, 0, 32 * sizeof(float), stream);
    gn_stats<<<dim3(32, 16), 256, 0, stream>>>(xb, stat);
    gn_ab<<<8, 256, 0, stream>>>(stat, vecb, vecb + 512, ab);

    const u16* qw = wgt;
    const u16* kw = wgt + 262144;
    const u16* vw = wgt + 2 * 262144;
    const u16* pw = wgt + 3 * 262144;
    const u16* qb2 = vecb + 1024, *kb2 = vecb + 1536, *vb2 = vecb + 2048, *pb2 = vecb + 2560;

    if (nb == 0) {
        // ---- lite path: exact R10 schedule (proven at this ws footprint) ----
        u16* qbuf = (u16*)w;  w += QS * 2;
        u16* kbuf = (u16*)w;  w += KS * 2;
        u16* vbuf = (u16*)w;  w += KS * 2;
        u16* obuf = (u16*)w;  w += QS * 2;
        u16* sbuf = (u16*)w;
        for (int b = 0; b < 4; b++) {
            gemm_k<2,2,4,4,0,2,1,0,0><<<dim3(54,4,1),256,0,stream>>>(
                kw, xb, kbuf, kb2, nullptr, ab, 512,0,6912, 512,1.f,0,b, 0,0,0,0);
            gemm_k<2,2,4,4,0,2,1,0,0><<<dim3(54,4,1),256,0,stream>>>(
                vw, xb, vbuf, vb2, nullptr, ab, 512,0,6912, 512,1.f,0,b, 0,0,0,0);
            gemm_k<2,2,4,4,0,2,1,0,0><<<dim3(18,4,1),256,0,stream>>>(
                qw, xb, qbuf, qb2, nullptr, ab, 512,0,2304, 512,1.f,2304,b, 0,0,0,0);
            gemm_k<2,2,4,4,1,0,0,0,0><<<dim3(54,18,1),256,0,stream>>>(
                qbuf, kbuf, sbuf, nullptr,nullptr,nullptr, 2304,6912,6912, 512,rs,0,b, 0,0,0,0);
            softmax_k<<<dim3(2304,1),256,0,stream>>>(sbuf, 0);
            gemm_k<1,4,4,1,0,1,0,0,0><<<dim3(36,8,1),256,0,stream>>>(
                vbuf, sbuf, obuf, nullptr,nullptr,nullptr, 6912,6912,2304, 6912,1.f,0,b, 0,0,0,0);
            gemm_k<2,2,4,2,0,0,3,1,0><<<dim3(36,4,1),256,0,stream>>>(
                pw, obuf, out + (size_t)b * PS, pb2, qbuf, nullptr,
                512,2304,2304, 512,1.f,0,b, 0,0,0,0);
        }
        return;
    }

    // ---- full path: z-batched, transposed operands, split-K O ----
    u16* qbuf = (u16*)w; w += (size_t)nb * QS * 2;
    u16* qT   = (u16*)w; w += (size_t)nb * QS * 2;
    u16* kbuf = (u16*)w; w += (size_t)nb * KS * 2;
    u16* kT   = (u16*)w; w += (size_t)nb * KS * 2;
    u16* vbuf = (u16*)w; w += (size_t)nb * KS * 2;
    u16* obT  = (u16*)w; w += (size_t)nb * QS * 2;
    u16* sbuf = (u16*)w; w += (size_t)nb * SS * 2;
    float* opart;
    if (nb == 4) opart = (float*)xb;              // xb dead after QKV (single group); 6*PS*4 == xb bytes
    else       { opart = (float*)w; w += (size_t)6 * PS * 4; }

    for (int g = 0; g < 4; g += nb) {
        gemm_k<2,2,4,4,0,2,1,0,0><<<dim3(54,4,nb),256,0,stream>>>(
            kw, xb, kbuf, kb2, nullptr, ab, 512,0,6912, 512,1.f,0,g, 0,0,KS,0);
        gemm_k<2,2,4,4,0,2,1,0,0><<<dim3(54,4,nb),256,0,stream>>>(
            vw, xb, vbuf, vb2, nullptr, ab, 512,0,6912, 512,1.f,0,g, 0,0,KS,0);
        gemm_k<2,2,4,4,0,2,1,0,0><<<dim3(18,4,nb),256,0,stream>>>(
            qw, xb, qbuf, qb2, nullptr, ab, 512,0,2304, 512,1.f,2304,g, 0,0,QS,0);
        tr_k<<<dim3(36,8,nb),256,0,stream>>>(qbuf, qT, 2304, QS, QS);
        tr_k<<<dim3(108,8,nb),256,0,stream>>>(kbuf, kT, 6912, KS, KS);
        // S[n][m] = qT[n][c] * kT[m][c]^T * rs  (both stagings vectorized)
        gemm_k<2,2,4,4,0,1,0,0,0><<<dim3(54,18,nb),256,0,stream>>>(
            qT, kT, sbuf, nullptr,nullptr,nullptr, 512,512,6912, 512,rs,0,g, QS,KS,SS,0);
        softmax_k<<<dim3(2304,nb),256,0,stream>>>(sbuf, SS);
        for (int bb = 0; bb < nb; bb++) {
            // O partial[c][n] over m-chunk z*1152, 6 chunks -> 864 blocks
            gemm_k<1,4,4,2,0,1,0,1,1><<<dim3(18,8,6),256,0,stream>>>(
                vbuf + (size_t)bb * KS, sbuf + (size_t)bb * SS, opart,
                nullptr,nullptr,nullptr, 6912,6912,2304, 1152,1.f,0,0, 0,0,PS,0);
            reduce6t<<<dim3(36,8),256,0,stream>>>(opart, obT + (size_t)bb * QS);
        }
        // out = pw @ O + pb + skip(q), f32; B=obT vectorized
        gemm_k<2,2,4,2,0,1,3,1,0><<<dim3(36,4,nb),256,0,stream>>>(
            pw, obT, out + (size_t)g * PS, pb2, qbuf, nullptr,
            512,512,2304, 512,1.f,0,g, 0,QS,PS,QS);
    }
}